// Round 4
// baseline (797.959 us; speedup 1.0000x reference)
//
#include <hip/hip_runtime.h>
#include <cstdint>
#include <cstddef>

typedef unsigned long long ull;

#define N 8192
#define NWORDS 128          // 8192 / 64
#define NPOST 2000
#define NMS_THR 0.7f

// All kernels: <=256 threads, <=12 KiB LDS (theory: 1024-thread + 64KiB-LDS
// launches were silently rejected in rounds 2/3 -> poison/zero outputs).

// ---------------- ws layout ----------------
// 0       : sc        f32[8192]     32 KiB   (score, -inf if invalid)
// 32768   : boxesRaw  float4[8192]  128 KiB
// 163840  : vsRaw     u8[8192]      8 KiB
// 172032  : bs        float4[8192]  128 KiB  (sorted clipped boxes)
// 303104  : area      f32[8192]     32 KiB   (sorted areas)
// 335872  : vsSorted  u8[8192]      8 KiB
// 524288  : mask      ull[8192*128] 8 MiB    (optional; only if ws fits)

// ---------------------------------------------------------------------------
__device__ __forceinline__ float4 decode_clip_box(const float4 L, bool* valid) {
#pragma clang fp contract(off)
  float cy = L.x, cx = L.y, h = L.z, w = L.w;
  float y1 = cy - 0.5f * h;
  float x1 = cx - 0.5f * w;
  float y2 = cy + 0.5f * h;
  float x2 = cx + 0.5f * w;
  *valid = ((y2 - y1) > 16.0f) && ((x2 - x1) > 16.0f);
  float4 b;
  b.x = fminf(fmaxf(y1, 0.0f), 800.0f);
  b.y = fminf(fmaxf(x1, 0.0f), 800.0f);
  b.z = fminf(fmaxf(y2, 0.0f), 800.0f);
  b.w = fminf(fmaxf(x2, 0.0f), 800.0f);
  return b;
}

__device__ __forceinline__ float box_area(const float4 b) {
#pragma clang fp contract(off)
  return (b.z - b.x) * (b.w - b.y);
}

__device__ __forceinline__ bool iou_gt_thr(const float4 a, float aa,
                                           const float4 b, float ab) {
#pragma clang fp contract(off)
  float iy = fminf(a.z, b.z) - fmaxf(a.x, b.x);
  float ix = fminf(a.w, b.w) - fmaxf(a.y, b.y);
  iy = fmaxf(iy, 0.0f);
  ix = fmaxf(ix, 0.0f);
  float inter = iy * ix;
  float uni = aa + ab - inter;
  return (inter > 0.0f) && (uni > 0.0f) && ((inter / uni) > NMS_THR);
}

// ---------------------------------------------------------------------------
// K1: decode + clip + score-with-validity
// ---------------------------------------------------------------------------
__global__ __launch_bounds__(256) void decode_kernel(
    const float* __restrict__ locs, const float* __restrict__ scores,
    float4* __restrict__ boxesRaw, unsigned char* __restrict__ vsRaw,
    float* __restrict__ sc) {
  int i = blockIdx.x * blockDim.x + threadIdx.x;
  if (i >= N) return;
  float4 L = reinterpret_cast<const float4*>(locs)[i];   // cy, cx, h, w
  bool valid;
  float4 b = decode_clip_box(L, &valid);
  boxesRaw[i] = b;
  vsRaw[i] = valid ? 1 : 0;
  sc[i] = valid ? scores[i] : -__builtin_inff();
}

// ---------------------------------------------------------------------------
// K2: O(N^2) rank-by-counting sort (descending score, stable by index),
// fused with the gather: bs[rank]=box, area[rank], vsSorted[rank].
// Total order: j precedes i  <=>  s_j > s_i  ||  (s_j == s_i && j < i).
// Matches jnp.argsort(-where(valid,s,-inf)) (stable mergesort).
// ---------------------------------------------------------------------------
__global__ __launch_bounds__(64) void ranksort_kernel(
    const float* __restrict__ sc, const float4* __restrict__ boxesRaw,
    const unsigned char* __restrict__ vsRaw,
    float4* __restrict__ bs, float* __restrict__ area,
    unsigned char* __restrict__ vsSorted) {
  int i = blockIdx.x * 64 + threadIdx.x;
  float si = sc[i];
  const float4* sc4 = reinterpret_cast<const float4*>(sc);
  int rank = 0;
  for (int q = 0; q < N / 4; ++q) {
    float4 v = sc4[q];
    int j = q * 4;
    rank += (v.x > si) || ((v.x == si) & ((j + 0) < i));
    rank += (v.y > si) || ((v.y == si) & ((j + 1) < i));
    rank += (v.z > si) || ((v.z == si) & ((j + 2) < i));
    rank += (v.w > si) || ((v.w == si) & ((j + 3) < i));
  }
  float4 b = boxesRaw[i];
  bs[rank] = b;
  area[rank] = box_area(b);
  vsSorted[rank] = vsRaw[i];
}

// ---------------------------------------------------------------------------
// K3: suppression bitmask (only if ws fits). bit c of mask[i][cb] =
// (j0+c > i) && IoU > thr.  Lower-triangle words written as 0 (never read).
// ---------------------------------------------------------------------------
__global__ __launch_bounds__(64) void mask_kernel(
    const float4* __restrict__ bs, const float* __restrict__ area,
    ull* __restrict__ mask) {
  int cb = blockIdx.x, rb = blockIdx.y;
  int t = threadIdx.x;
  int i = rb * 64 + t;
  if (cb < rb) {
    mask[(size_t)i * NWORDS + cb] = 0ull;
    return;
  }
  __shared__ float4 sb[64];
  __shared__ float sa[64];
  int j0 = cb * 64;
  sb[t] = bs[j0 + t];
  sa[t] = area[j0 + t];
  float4 r = bs[i];
  float ai = area[i];
  __syncthreads();
  ull bits = 0;
  for (int c = 0; c < 64; ++c) {
    if ((j0 + c) > i && iou_gt_thr(r, ai, sb[c], sa[c])) bits |= 1ull << c;
  }
  mask[(size_t)i * NWORDS + cb] = bits;
}

// ---------------------------------------------------------------------------
// K4a: greedy scan using the precomputed mask.  256 thr, ~11 KiB LDS.
// Anomaly beacon: out[0] = 1e9 + nValid*1e5 + min(total,2000)*10.
// ---------------------------------------------------------------------------
__global__ __launch_bounds__(256) void scan_mask_kernel(
    const ull* __restrict__ mask, const unsigned char* __restrict__ vsSorted,
    const float4* __restrict__ bs, float* __restrict__ out) {
  __shared__ ull sRemv[NWORDS];
  __shared__ ull sPart[2][NWORDS];
  __shared__ int sKeptList[NPOST];
  __shared__ ull sKeptW;
  __shared__ int sKeptBase;
  __shared__ int sStop;
  __shared__ int sNV;
  int tid = threadIdx.x;

  if (tid == 0) { sKeptBase = 0; sStop = 0; sKeptW = 0; sNV = 0; }
  __syncthreads();
  if (tid < NWORDS) {            // suppressed0 = !valid
    ull wbits = 0;
    for (int b = 0; b < 64; ++b)
      if (!vsSorted[tid * 64 + b]) wbits |= 1ull << b;
    sRemv[tid] = wbits;
    atomicAdd(&sNV, 64 - (int)__popcll(wbits));
  }

  for (int w = 0; w < NWORDS; ++w) {
    __syncthreads();
    if (sStop) break;
    int i0 = w * 64;
    if (tid < 64) {              // wave 0: serial within-word resolution
      int lane = tid;
      ull dg = mask[(size_t)(i0 + lane) * NWORDS + w];
      ull cur = sRemv[w];        // uniform
      ull keptw = 0;
      ull avail = ~cur;
      while (avail) {
        int b = (int)__builtin_ctzll(avail);
        keptw |= 1ull << b;
        unsigned lo32 = __builtin_amdgcn_readlane((int)(unsigned)(dg & 0xFFFFFFFFull), b);
        unsigned hi32 = __builtin_amdgcn_readlane((int)(unsigned)(dg >> 32), b);
        cur |= (((ull)hi32) << 32) | (ull)lo32;
        avail = (b >= 63) ? 0ull : ((~cur) & (~0ull << (b + 1)));
      }
      int base = sKeptBase;      // wave-ordered read before lane 0's write
      if ((keptw >> lane) & 1ull) {
        int rank = base + (int)__popcll(keptw & ((1ull << lane) - 1ull));
        if (rank < NPOST) sKeptList[rank] = i0 + lane;
      }
      if (lane == 0) {
        sKeptW = keptw;
        sRemv[w] = cur;
        int nb = base + (int)__popcll(keptw);
        sKeptBase = nb;
        if (nb >= NPOST) sStop = 1;
      }
    }
    __syncthreads();
    if (sStop) break;
    ull kw = sKeptW;
    if (kw) {                    // cross-word suppression, words > w only
      int wd = tid & (NWORDS - 1);
      int g = tid >> 7;
      if (wd > w) {
        ull acc = 0;
        int cnt = 0;
        #pragma unroll
        for (int b = 0; b < 64; ++b) {
          if ((kw >> b) & 1ull) {
            if ((cnt & 1) == g) acc |= mask[(size_t)(i0 + b) * NWORDS + wd];
            ++cnt;
          }
        }
        sPart[g][wd] = acc;
      }
      __syncthreads();
      if (tid > w && tid < NWORDS) sRemv[tid] |= sPart[0][tid] | sPart[1][tid];
    }
  }

  __syncthreads();
  int total = sKeptBase;
  if (total > NPOST) total = NPOST;
  for (int r = tid; r < NPOST; r += 256) {
    float4 v = make_float4(0.0f, 0.0f, 0.0f, 0.0f);
    if (r < total) v = bs[sKeptList[r]];
    reinterpret_cast<float4*>(out)[r] = v;
  }
  int nv = sNV;
  bool anomaly = (total == 0) || (nv == 0) || (nv == N);
  if (anomaly && tid == 0)
    out[0] = 1.0e9f + (float)nv * 1.0e5f + (float)total * 10.0f;
}

// ---------------------------------------------------------------------------
// K4b: greedy scan computing IoU on the fly (no mask workspace needed).
// Beacon base 3e9.
// ---------------------------------------------------------------------------
__global__ __launch_bounds__(256) void scan_nomask_kernel(
    const float4* __restrict__ bs, const float* __restrict__ area,
    const unsigned char* __restrict__ vsSorted, float* __restrict__ out) {
  __shared__ ull sRemv[NWORDS];
  __shared__ float4 swb[64];
  __shared__ float swa[64];
  __shared__ int sKeptList[NPOST];
  __shared__ ull sKeptW;
  __shared__ int sKeptBase;
  __shared__ int sStop;
  __shared__ int sNV;
  int tid = threadIdx.x;

  if (tid == 0) { sKeptBase = 0; sStop = 0; sKeptW = 0; sNV = 0; }
  __syncthreads();
  if (tid < NWORDS) {
    ull wbits = 0;
    for (int b = 0; b < 64; ++b)
      if (!vsSorted[tid * 64 + b]) wbits |= 1ull << b;
    sRemv[tid] = wbits;
    atomicAdd(&sNV, 64 - (int)__popcll(wbits));
  }

  for (int w = 0; w < NWORDS; ++w) {
    __syncthreads();
    if (sStop) break;
    int i0 = w * 64;
    if (tid < 64) {              // wave 0: stage boxes + resolve word
      swb[tid] = bs[i0 + tid];
      swa[tid] = area[i0 + tid];
      int lane = tid;
      float4 br = swb[lane];     // same-wave LDS, lockstep-safe
      float ar = swa[lane];
      ull dg = 0;
      for (int c = 0; c < 64; ++c)
        if (c > lane && iou_gt_thr(br, ar, swb[c], swa[c])) dg |= 1ull << c;
      ull cur = sRemv[w];
      ull keptw = 0;
      ull avail = ~cur;
      while (avail) {
        int b = (int)__builtin_ctzll(avail);
        keptw |= 1ull << b;
        unsigned lo32 = __builtin_amdgcn_readlane((int)(unsigned)(dg & 0xFFFFFFFFull), b);
        unsigned hi32 = __builtin_amdgcn_readlane((int)(unsigned)(dg >> 32), b);
        cur |= (((ull)hi32) << 32) | (ull)lo32;
        avail = (b >= 63) ? 0ull : ((~cur) & (~0ull << (b + 1)));
      }
      int base = sKeptBase;
      if ((keptw >> lane) & 1ull) {
        int rank = base + (int)__popcll(keptw & ((1ull << lane) - 1ull));
        if (rank < NPOST) sKeptList[rank] = i0 + lane;
      }
      if (lane == 0) {
        sKeptW = keptw;
        sRemv[w] = cur;
        int nb = base + (int)__popcll(keptw);
        sKeptBase = nb;
        if (nb >= NPOST) sStop = 1;
      }
    }
    __syncthreads();
    if (sStop) break;
    ull kw = sKeptW;
    if (kw) {                    // cross-word: recompute IoU vs kept set
      for (int j = i0 + 64 + tid; j < N; j += 256) {
        ull rm = sRemv[j >> 6];
        if ((rm >> (j & 63)) & 1ull) continue;   // already suppressed
        float4 bj = bs[j];
        float aj = area[j];
        ull t = kw;
        bool sup = false;
        while (t) {
          int b = (int)__builtin_ctzll(t);
          t &= t - 1;
          if (iou_gt_thr(bj, aj, swb[b], swa[b])) { sup = true; break; }
        }
        if (sup) atomicOr(&sRemv[j >> 6], 1ull << (j & 63));
      }
    }
  }

  __syncthreads();
  int total = sKeptBase;
  if (total > NPOST) total = NPOST;
  for (int r = tid; r < NPOST; r += 256) {
    float4 v = make_float4(0.0f, 0.0f, 0.0f, 0.0f);
    if (r < total) v = bs[sKeptList[r]];
    reinterpret_cast<float4*>(out)[r] = v;
  }
  int nv = sNV;
  bool anomaly = (total == 0) || (nv == 0) || (nv == N);
  if (anomaly && tid == 0)
    out[0] = 3.0e9f + (float)nv * 1.0e5f + (float)total * 10.0f;
}

// ---------------------------------------------------------------------------
extern "C" void kernel_launch(void* const* d_in, const int* in_sizes, int n_in,
                              void* d_out, int out_size, void* d_ws, size_t ws_size,
                              hipStream_t stream) {
  const float* locs   = (const float*)d_in[0];   // (8192,4) cy,cx,h,w
  const float* scores = (const float*)d_in[1];   // (8192,)

  char* ws = (char*)d_ws;
  float*         sc       = (float*)(ws + 0);
  float4*        boxesRaw = (float4*)(ws + 32768);
  unsigned char* vsRaw    = (unsigned char*)(ws + 163840);
  float4*        bs       = (float4*)(ws + 172032);
  float*         area     = (float*)(ws + 303104);
  unsigned char* vsSorted = (unsigned char*)(ws + 335872);
  ull*           mask     = (ull*)(ws + 524288);

  const size_t WS_MASK_NEEDED = 524288 + (size_t)N * NWORDS * sizeof(ull); // 8,912,896

  decode_kernel<<<N / 256, 256, 0, stream>>>(locs, scores, boxesRaw, vsRaw, sc);
  ranksort_kernel<<<N / 64, 64, 0, stream>>>(sc, boxesRaw, vsRaw, bs, area, vsSorted);
  if (ws_size >= WS_MASK_NEEDED) {
    mask_kernel<<<dim3(NWORDS, NWORDS), 64, 0, stream>>>(bs, area, mask);
    scan_mask_kernel<<<1, 256, 0, stream>>>(mask, vsSorted, bs, (float*)d_out);
  } else {
    scan_nomask_kernel<<<1, 256, 0, stream>>>(bs, area, vsSorted, (float*)d_out);
  }
}

// Round 5
// 358.545 us; speedup vs baseline: 2.2255x; 2.2255x over previous
//
#include <hip/hip_runtime.h>
#include <cstdint>
#include <cstddef>

typedef unsigned long long ull;
typedef unsigned short u16;

#define N 8192
#define NWORDS 128          // 8192 / 64
#define NPOST 2000
#define NMS_THR 0.7f
#define SPLIT 4
#define SLICE (N / SPLIT)   // 2048

// All kernels <=256 threads, <=12 KiB LDS (1024-thr/64KiB launches failed
// silently in rounds 2/3).

// ---------------- ws layout ----------------
// 0      : sc        f32[8192]      32 KiB  (score, -inf if invalid)
// 32768  : boxesRaw  float4[8192]   128 KiB
// 163840 : vsRaw     u8[8192]       8 KiB
// 172032 : bs        float4[8192]   128 KiB (sorted clipped boxes)
// 303104 : area      f32[8192]      32 KiB  (sorted areas)
// 335872 : invBits   ull[128]       1 KiB   (sorted-order invalid bitmap)
// 336896 : partial   i32[4*8192]    128 KiB (rank partial counts)
// 524288 : mask      ull[8192*128]  8 MiB   (upper triangle + diag only)

// ---------------------------------------------------------------------------
__device__ __forceinline__ float4 decode_clip_box(const float4 L, bool* valid) {
#pragma clang fp contract(off)
  float cy = L.x, cx = L.y, h = L.z, w = L.w;
  float y1 = cy - 0.5f * h;
  float x1 = cx - 0.5f * w;
  float y2 = cy + 0.5f * h;
  float x2 = cx + 0.5f * w;
  *valid = ((y2 - y1) > 16.0f) && ((x2 - x1) > 16.0f);
  float4 b;
  b.x = fminf(fmaxf(y1, 0.0f), 800.0f);
  b.y = fminf(fmaxf(x1, 0.0f), 800.0f);
  b.z = fminf(fmaxf(y2, 0.0f), 800.0f);
  b.w = fminf(fmaxf(x2, 0.0f), 800.0f);
  return b;
}

__device__ __forceinline__ float box_area(const float4 b) {
#pragma clang fp contract(off)
  return (b.z - b.x) * (b.w - b.y);
}

__device__ __forceinline__ bool iou_gt_thr(const float4 a, float aa,
                                           const float4 b, float ab) {
#pragma clang fp contract(off)
  float iy = fminf(a.z, b.z) - fmaxf(a.x, b.x);
  float ix = fminf(a.w, b.w) - fmaxf(a.y, b.y);
  iy = fmaxf(iy, 0.0f);
  ix = fmaxf(ix, 0.0f);
  float inter = iy * ix;
  float uni = aa + ab - inter;
  return (inter > 0.0f) && (uni > 0.0f) && ((inter / uni) > NMS_THR);
}

// ---------------------------------------------------------------------------
// K1: decode + clip + score; also zeroes invBits (graph-replay determinism).
// ---------------------------------------------------------------------------
__global__ __launch_bounds__(256) void decode_kernel(
    const float* __restrict__ locs, const float* __restrict__ scores,
    float4* __restrict__ boxesRaw, unsigned char* __restrict__ vsRaw,
    float* __restrict__ sc, ull* __restrict__ invBits) {
  int i = blockIdx.x * 256 + threadIdx.x;
  if (i < NWORDS) invBits[i] = 0ull;
  if (i >= N) return;
  float4 L = reinterpret_cast<const float4*>(locs)[i];   // cy, cx, h, w
  bool valid;
  float4 b = decode_clip_box(L, &valid);
  boxesRaw[i] = b;
  vsRaw[i] = valid ? 1 : 0;
  sc[i] = valid ? scores[i] : -__builtin_inff();
}

// ---------------------------------------------------------------------------
// K2: partial rank counts.  Total order: j precedes i <=> s_j > s_i ||
// (s_j == s_i && j < i)  — matches stable argsort of -where(valid,s,-inf).
// ---------------------------------------------------------------------------
__global__ __launch_bounds__(256) void rankpart_kernel(
    const float* __restrict__ sc, int* __restrict__ partial) {
  int i = blockIdx.x * 256 + threadIdx.x;   // box index
  int s = blockIdx.y;                        // slice index
  float si = sc[i];
  const float4* sc4 = reinterpret_cast<const float4*>(sc + s * SLICE);
  int j0 = s * SLICE;
  int cnt = 0;
  for (int q = 0; q < SLICE / 4; ++q) {
    float4 v = sc4[q];
    int j = j0 + q * 4;
    cnt += (v.x > si) || ((v.x == si) & ((j + 0) < i));
    cnt += (v.y > si) || ((v.y == si) & ((j + 1) < i));
    cnt += (v.z > si) || ((v.z == si) & ((j + 2) < i));
    cnt += (v.w > si) || ((v.w == si) & ((j + 3) < i));
  }
  partial[s * N + i] = cnt;
}

// ---------------------------------------------------------------------------
// K3: gather into sorted order; build invalid bitmap in sorted positions.
// Ranks are a permutation (strict total order) -> bs/area fully rewritten.
// ---------------------------------------------------------------------------
__global__ __launch_bounds__(256) void gather_kernel(
    const int* __restrict__ partial, const float4* __restrict__ boxesRaw,
    const unsigned char* __restrict__ vsRaw,
    float4* __restrict__ bs, float* __restrict__ area, ull* __restrict__ invBits) {
  int i = blockIdx.x * 256 + threadIdx.x;
  int r = partial[i] + partial[N + i] + partial[2 * N + i] + partial[3 * N + i];
  float4 b = boxesRaw[i];
  bs[r] = b;
  area[r] = box_area(b);
  if (!vsRaw[i]) atomicOr(&invBits[r >> 6], 1ull << (r & 63));
}

// ---------------------------------------------------------------------------
// K4: suppression bitmask, upper triangle + diagonal only (lower never read).
// ---------------------------------------------------------------------------
__global__ __launch_bounds__(64) void mask_kernel(
    const float4* __restrict__ bs, const float* __restrict__ area,
    ull* __restrict__ mask) {
  int cb = blockIdx.x, rb = blockIdx.y;
  if (cb < rb) return;                 // never read by scan
  int t = threadIdx.x;
  int i = rb * 64 + t;
  __shared__ float4 sb[64];
  __shared__ float sa[64];
  int j0 = cb * 64;
  sb[t] = bs[j0 + t];
  sa[t] = area[j0 + t];
  float4 r = bs[i];
  float ai = area[i];
  __syncthreads();
  ull bits = 0;
  for (int c = 0; c < 64; ++c) {
    if ((j0 + c) > i && iou_gt_thr(r, ai, sb[c], sa[c])) bits |= 1ull << c;
  }
  mask[(size_t)i * NWORDS + cb] = bits;
}

// ---------------------------------------------------------------------------
// K5: greedy scan.  Wave 0: serial within-word resolve (diag prefetched by
// wave 1 during the previous word).  Cross-word OR: compacted kept list in
// LDS, branch-free 4-deep pipelined loads, LDS atomicOr.  Early stop at 2000.
// ---------------------------------------------------------------------------
__global__ __launch_bounds__(256) void scan_mask_kernel(
    const ull* __restrict__ mask, const ull* __restrict__ invBits,
    const float4* __restrict__ bs, float* __restrict__ out) {
  __shared__ ull sRemv[NWORDS];
  __shared__ ull sDiag[2][64];
  __shared__ u16 sWK[64];
  __shared__ int sKeptList[NPOST];
  __shared__ int sNK;
  __shared__ int sKeptBase;
  __shared__ int sStop;
  int tid = threadIdx.x;

  if (tid == 0) { sKeptBase = 0; sStop = 0; sNK = 0; }
  if (tid < NWORDS) sRemv[tid] = invBits[tid];     // suppressed0 = !valid
  if (tid >= 64 && tid < 128)                      // prefetch diag of word 0
    sDiag[0][tid - 64] = mask[(size_t)(tid - 64) * NWORDS + 0];
  __syncthreads();

  for (int w = 0; w < NWORDS; ++w) {
    int i0 = w * 64;
    int buf = w & 1;
    if (tid < 64) {
      // ---- wave 0: serial within-word greedy resolve (all VALU, no memory)
      int lane = tid;
      ull dg = sDiag[buf][lane];
      ull cur = sRemv[w];                          // uniform broadcast
      ull keptw = 0;
      ull avail = ~cur;
      while (avail) {
        int b = (int)__builtin_ctzll(avail);       // uniform
        keptw |= 1ull << b;
        unsigned lo32 = __builtin_amdgcn_readlane((int)(unsigned)(dg & 0xFFFFFFFFull), b);
        unsigned hi32 = __builtin_amdgcn_readlane((int)(unsigned)(dg >> 32), b);
        cur |= (((ull)hi32) << 32) | (ull)lo32;
        avail = (b >= 63) ? 0ull : ((~cur) & (~0ull << (b + 1)));
      }
      int base = sKeptBase;        // wave-ordered read before lane 0's write
      int below = (int)__popcll(keptw & ((1ull << lane) - 1ull));
      if ((keptw >> lane) & 1ull) {
        int rank = base + below;
        if (rank < NPOST) sKeptList[rank] = i0 + lane;
        sWK[below] = (u16)(i0 + lane);             // compacted kept rows
      }
      if (lane == 0) {
        int nk = (int)__popcll(keptw);
        sNK = nk;
        int nb = base + nk;
        sKeptBase = nb;
        if (nb >= NPOST) sStop = 1;
      }
    } else if (tid < 128 && w + 1 < NWORDS) {
      // ---- wave 1: prefetch next word's diagonal (overlaps serial resolve)
      int lane = tid - 64;
      sDiag[buf ^ 1][lane] = mask[(size_t)(i0 + 64 + lane) * NWORDS + (w + 1)];
    }
    __syncthreads();
    if (sStop) break;
    int nk = sNK;
    if (nk) {
      // ---- cross-word suppression: branch-free, 4 loads in flight
      int wd = tid & (NWORDS - 1);
      int g = tid >> 7;                            // 2 groups over kept list
      if (wd > w) {
        const ull* mw = mask + wd;
        ull acc = 0;
        int k = g;
        for (; k + 6 < nk; k += 8) {
          ull a0 = mw[(size_t)sWK[k] * NWORDS];
          ull a1 = mw[(size_t)sWK[k + 2] * NWORDS];
          ull a2 = mw[(size_t)sWK[k + 4] * NWORDS];
          ull a3 = mw[(size_t)sWK[k + 6] * NWORDS];
          acc |= a0 | a1;
          acc |= a2 | a3;
        }
        for (; k < nk; k += 2) acc |= mw[(size_t)sWK[k] * NWORDS];
        if (acc) atomicOr(&sRemv[wd], acc);
      }
    }
    __syncthreads();
  }

  __syncthreads();
  int total = sKeptBase;
  if (total > NPOST) total = NPOST;
  for (int r = tid; r < NPOST; r += 256) {
    float4 v = make_float4(0.0f, 0.0f, 0.0f, 0.0f);
    if (r < total) v = bs[sKeptList[r]];
    reinterpret_cast<float4*>(out)[r] = v;
  }
}

// ---------------------------------------------------------------------------
extern "C" void kernel_launch(void* const* d_in, const int* in_sizes, int n_in,
                              void* d_out, int out_size, void* d_ws, size_t ws_size,
                              hipStream_t stream) {
  const float* locs   = (const float*)d_in[0];   // (8192,4) cy,cx,h,w
  const float* scores = (const float*)d_in[1];   // (8192,)

  char* ws = (char*)d_ws;
  float*         sc       = (float*)(ws + 0);
  float4*        boxesRaw = (float4*)(ws + 32768);
  unsigned char* vsRaw    = (unsigned char*)(ws + 163840);
  float4*        bs       = (float4*)(ws + 172032);
  float*         area     = (float*)(ws + 303104);
  ull*           invBits  = (ull*)(ws + 335872);
  int*           partial  = (int*)(ws + 336896);
  ull*           mask     = (ull*)(ws + 524288);

  decode_kernel<<<N / 256, 256, 0, stream>>>(locs, scores, boxesRaw, vsRaw, sc, invBits);
  rankpart_kernel<<<dim3(N / 256, SPLIT), 256, 0, stream>>>(sc, partial);
  gather_kernel<<<N / 256, 256, 0, stream>>>(partial, boxesRaw, vsRaw, bs, area, invBits);
  mask_kernel<<<dim3(NWORDS, NWORDS), 64, 0, stream>>>(bs, area, mask);
  scan_mask_kernel<<<1, 256, 0, stream>>>(mask, invBits, bs, (float*)d_out);
}

// Round 6
// 347.111 us; speedup vs baseline: 2.2989x; 1.0329x over previous
//
#include <hip/hip_runtime.h>
#include <cstdint>
#include <cstddef>

typedef unsigned long long ull;
typedef unsigned short u16;

#define N 8192
#define NWORDS 128          // 8192 / 64
#define NPOST 2000
#define NMS_THR 0.7f
#define SPLIT 4
#define SLICE (N / SPLIT)   // 2048

// All kernels <=256 threads, <=12 KiB LDS (1024-thr/64KiB launches failed
// silently in rounds 2/3).

// ---------------- ws layout ----------------
// 0      : sc        f32[8192]      32 KiB  (score, -inf if invalid)
// 32768  : boxesRaw  float4[8192]   128 KiB
// 163840 : vsRaw     u8[8192]       8 KiB
// 172032 : bs        float4[8192]   128 KiB (sorted clipped boxes)
// 303104 : area      f32[8192]      32 KiB  (sorted areas)
// 335872 : invBits   ull[128]       1 KiB   (sorted-order invalid bitmap)
// 336896 : partial   i32[4*8192]    128 KiB (rank partial counts)
// 524288 : mask      ull[8192*128]  8 MiB   (upper triangle + diag only)

// ---------------------------------------------------------------------------
__device__ __forceinline__ float4 decode_clip_box(const float4 L, bool* valid) {
#pragma clang fp contract(off)
  float cy = L.x, cx = L.y, h = L.z, w = L.w;
  float y1 = cy - 0.5f * h;
  float x1 = cx - 0.5f * w;
  float y2 = cy + 0.5f * h;
  float x2 = cx + 0.5f * w;
  *valid = ((y2 - y1) > 16.0f) && ((x2 - x1) > 16.0f);
  float4 b;
  b.x = fminf(fmaxf(y1, 0.0f), 800.0f);
  b.y = fminf(fmaxf(x1, 0.0f), 800.0f);
  b.z = fminf(fmaxf(y2, 0.0f), 800.0f);
  b.w = fminf(fmaxf(x2, 0.0f), 800.0f);
  return b;
}

__device__ __forceinline__ float box_area(const float4 b) {
#pragma clang fp contract(off)
  return (b.z - b.x) * (b.w - b.y);
}

__device__ __forceinline__ bool iou_gt_thr(const float4 a, float aa,
                                           const float4 b, float ab) {
#pragma clang fp contract(off)
  float iy = fminf(a.z, b.z) - fmaxf(a.x, b.x);
  float ix = fminf(a.w, b.w) - fmaxf(a.y, b.y);
  iy = fmaxf(iy, 0.0f);
  ix = fmaxf(ix, 0.0f);
  float inter = iy * ix;
  float uni = aa + ab - inter;
  return (inter > 0.0f) && (uni > 0.0f) && ((inter / uni) > NMS_THR);
}

// ---------------------------------------------------------------------------
// K1: decode + clip + score; also zeroes invBits (graph-replay determinism).
// ---------------------------------------------------------------------------
__global__ __launch_bounds__(256) void decode_kernel(
    const float* __restrict__ locs, const float* __restrict__ scores,
    float4* __restrict__ boxesRaw, unsigned char* __restrict__ vsRaw,
    float* __restrict__ sc, ull* __restrict__ invBits) {
  int i = blockIdx.x * 256 + threadIdx.x;
  if (i < NWORDS) invBits[i] = 0ull;
  if (i >= N) return;
  float4 L = reinterpret_cast<const float4*>(locs)[i];   // cy, cx, h, w
  bool valid;
  float4 b = decode_clip_box(L, &valid);
  boxesRaw[i] = b;
  vsRaw[i] = valid ? 1 : 0;
  sc[i] = valid ? scores[i] : -__builtin_inff();
}

// ---------------------------------------------------------------------------
// K2: partial rank counts.  Total order: j precedes i <=> s_j > s_i ||
// (s_j == s_i && j < i)  — matches stable argsort of -where(valid,s,-inf).
// ---------------------------------------------------------------------------
__global__ __launch_bounds__(256) void rankpart_kernel(
    const float* __restrict__ sc, int* __restrict__ partial) {
  int i = blockIdx.x * 256 + threadIdx.x;   // box index
  int s = blockIdx.y;                        // slice index
  float si = sc[i];
  const float4* sc4 = reinterpret_cast<const float4*>(sc + s * SLICE);
  int j0 = s * SLICE;
  int cnt = 0;
  for (int q = 0; q < SLICE / 4; ++q) {
    float4 v = sc4[q];
    int j = j0 + q * 4;
    cnt += (v.x > si) || ((v.x == si) & ((j + 0) < i));
    cnt += (v.y > si) || ((v.y == si) & ((j + 1) < i));
    cnt += (v.z > si) || ((v.z == si) & ((j + 2) < i));
    cnt += (v.w > si) || ((v.w == si) & ((j + 3) < i));
  }
  partial[s * N + i] = cnt;
}

// ---------------------------------------------------------------------------
// K3: gather into sorted order; build invalid bitmap in sorted positions.
// ---------------------------------------------------------------------------
__global__ __launch_bounds__(256) void gather_kernel(
    const int* __restrict__ partial, const float4* __restrict__ boxesRaw,
    const unsigned char* __restrict__ vsRaw,
    float4* __restrict__ bs, float* __restrict__ area, ull* __restrict__ invBits) {
  int i = blockIdx.x * 256 + threadIdx.x;
  int r = partial[i] + partial[N + i] + partial[2 * N + i] + partial[3 * N + i];
  float4 b = boxesRaw[i];
  bs[r] = b;
  area[r] = box_area(b);
  if (!vsRaw[i]) atomicOr(&invBits[r >> 6], 1ull << (r & 63));
}

// ---------------------------------------------------------------------------
// K4: suppression bitmask, upper triangle + diagonal only (lower never read).
// ---------------------------------------------------------------------------
__global__ __launch_bounds__(64) void mask_kernel(
    const float4* __restrict__ bs, const float* __restrict__ area,
    ull* __restrict__ mask) {
  int cb = blockIdx.x, rb = blockIdx.y;
  if (cb < rb) return;                 // never read by scan
  int t = threadIdx.x;
  int i = rb * 64 + t;
  __shared__ float4 sb[64];
  __shared__ float sa[64];
  int j0 = cb * 64;
  sb[t] = bs[j0 + t];
  sa[t] = area[j0 + t];
  float4 r = bs[i];
  float ai = area[i];
  __syncthreads();
  ull bits = 0;
  for (int c = 0; c < 64; ++c) {
    if ((j0 + c) > i && iou_gt_thr(r, ai, sb[c], sa[c])) bits |= 1ull << c;
  }
  mask[(size_t)i * NWORDS + cb] = bits;
}

// ---------------------------------------------------------------------------
// K5: greedy scan.
//  Phase A (wave 0): within-word resolve via ballot fast path (no internal
//    conflict -> kept = avail in O(1)); rare conflict words use a 64-ballot
//    bit-transpose + fixpoint  kept <- avail & ~N+(kept)  (== greedy by
//    prefix-stabilization; <=64 iters).
//  Phase B (all 256): cross-word OR with 32 loads in flight per thread
//    (single vmcnt wait); wave 3 additionally prefetches next word's diag.
// ---------------------------------------------------------------------------
__global__ __launch_bounds__(256) void scan_mask_kernel(
    const ull* __restrict__ mask, const ull* __restrict__ invBits,
    const float4* __restrict__ bs, float* __restrict__ out) {
  __shared__ ull sRemv[NWORDS];
  __shared__ ull sDiag[2][64];
  __shared__ u16 sWK[64];
  __shared__ int sKeptList[NPOST];
  __shared__ int sNK;
  __shared__ int sKeptBase;
  __shared__ int sStop;
  int tid = threadIdx.x;

  if (tid == 0) { sKeptBase = 0; sStop = 0; sNK = 0; }
  if (tid < NWORDS) sRemv[tid] = invBits[tid];     // suppressed0 = !valid
  if (tid >= 64 && tid < 128)                      // prefetch diag of word 0
    sDiag[0][tid - 64] = mask[(size_t)(tid - 64) * NWORDS + 0];
  __syncthreads();

  for (int w = 0; w < NWORDS; ++w) {
    int i0 = w * 64;
    int buf = w & 1;
    if (tid < 64) {
      // ---- Phase A: wave 0 within-word greedy resolve
      int lane = tid;
      ull dg = sDiag[buf][lane];         // rows I suppress (bits > lane only)
      ull avail = ~sRemv[w];             // uniform
      ull kept;
      ull conflict = __ballot(((dg & avail) != 0ull) && ((avail >> lane) & 1ull));
      if (conflict == 0ull) {
        kept = avail;                    // fast path: no internal suppression
      } else {
        // transpose dg so each lane knows its suppressors (all < lane)
        ull dgT = 0ull;
        #pragma unroll
        for (int c = 0; c < 64; ++c) {
          ull t = __ballot((dg >> c) & 1ull);
          if (lane == c) dgT = t;
        }
        kept = avail;
        while (true) {                   // fixpoint == greedy (<=64 iters)
          bool sup = (dgT & kept) != 0ull;
          ull kn = avail & ~__ballot(sup);
          if (kn == kept) break;
          kept = kn;
        }
      }
      int base = sKeptBase;              // wave-ordered read before write below
      int below = (int)__popcll(kept & ((1ull << lane) - 1ull));
      if ((kept >> lane) & 1ull) {
        int rank = base + below;
        if (rank < NPOST) sKeptList[rank] = i0 + lane;
        sWK[below] = (u16)(i0 + lane);   // compacted kept rows
      }
      if (lane == 0) {
        int nk = (int)__popcll(kept);
        sNK = nk;
        int nb = base + nk;
        sKeptBase = nb;
        if (nb >= NPOST) sStop = 1;
      }
    }
    __syncthreads();
    if (sStop) break;
    int nk = sNK;
    // ---- Phase B: prefetch next diag (wave 3 extra duty) + cross-word OR
    if (tid >= 192 && w + 1 < NWORDS) {
      int lane2 = tid - 192;
      sDiag[buf ^ 1][lane2] = mask[(size_t)(i0 + 64 + lane2) * NWORDS + (w + 1)];
    }
    if (nk) {
      int wd = tid & (NWORDS - 1);
      int g = tid >> 7;                  // 2 groups interleave the kept list
      if (wd > w) {
        const ull* mw = mask + wd;
        ull acc = 0;
        #pragma unroll
        for (int it = 0; it < 32; ++it) {          // all loads in flight
          int k = 2 * it + g;
          int kk = (k < nk) ? k : (nk - 1);        // clamp: OR idempotent
          acc |= mw[(size_t)sWK[kk] * NWORDS];
        }
        if (acc) atomicOr(&sRemv[wd], acc);
      }
    }
    __syncthreads();
  }

  __syncthreads();
  int total = sKeptBase;
  if (total > NPOST) total = NPOST;
  for (int r = tid; r < NPOST; r += 256) {
    float4 v = make_float4(0.0f, 0.0f, 0.0f, 0.0f);
    if (r < total) v = bs[sKeptList[r]];
    reinterpret_cast<float4*>(out)[r] = v;
  }
}

// ---------------------------------------------------------------------------
extern "C" void kernel_launch(void* const* d_in, const int* in_sizes, int n_in,
                              void* d_out, int out_size, void* d_ws, size_t ws_size,
                              hipStream_t stream) {
  const float* locs   = (const float*)d_in[0];   // (8192,4) cy,cx,h,w
  const float* scores = (const float*)d_in[1];   // (8192,)

  char* ws = (char*)d_ws;
  float*         sc       = (float*)(ws + 0);
  float4*        boxesRaw = (float4*)(ws + 32768);
  unsigned char* vsRaw    = (unsigned char*)(ws + 163840);
  float4*        bs       = (float4*)(ws + 172032);
  float*         area     = (float*)(ws + 303104);
  ull*           invBits  = (ull*)(ws + 335872);
  int*           partial  = (int*)(ws + 336896);
  ull*           mask     = (ull*)(ws + 524288);

  decode_kernel<<<N / 256, 256, 0, stream>>>(locs, scores, boxesRaw, vsRaw, sc, invBits);
  rankpart_kernel<<<dim3(N / 256, SPLIT), 256, 0, stream>>>(sc, partial);
  gather_kernel<<<N / 256, 256, 0, stream>>>(partial, boxesRaw, vsRaw, bs, area, invBits);
  mask_kernel<<<dim3(NWORDS, NWORDS), 64, 0, stream>>>(bs, area, mask);
  scan_mask_kernel<<<1, 256, 0, stream>>>(mask, invBits, bs, (float*)d_out);
}

// Round 7
// 166.956 us; speedup vs baseline: 4.7795x; 2.0791x over previous
//
#include <hip/hip_runtime.h>
#include <cstdint>
#include <cstddef>

typedef unsigned long long ull;
typedef unsigned short u16;

#define N 8192
#define NWORDS 128          // 8192 / 64
#define NPOST 2000
#define NMS_THR 0.7f
#define SPLIT 8
#define SLICE (N / SPLIT)   // 1024
#define GROUP 4             // words per sequential group
#define GBOX 256            // boxes per group
#define NGROUPS (NWORDS / GROUP)  // 32

// All kernels <=256 threads (1024-thr/64KiB launches failed silently in r2/3).

// ---------------- ws layout (same extent as rounds 4-6) ----------------
// 0      : sc        f32[8192]      32 KiB  (score, -inf if invalid)
// 32768  : boxesRaw  float4[8192]   128 KiB
// 163840 : vsRaw     u8[8192]       8 KiB
// 172032 : bs        float4[8192]   128 KiB (sorted clipped boxes)
// 303104 : area      f32[8192]      32 KiB  (sorted areas)
// 335872 : invBits   ull[128]       1 KiB   (sorted-order invalid bitmap)
// 336896 : partial   u16[8*8192]    128 KiB (rank partial counts)
// 524288 : maskT     ull[128*8192]  8 MiB   TRANSPOSED: maskT[cb*N + row]

// ---------------------------------------------------------------------------
__device__ __forceinline__ float4 decode_clip_box(const float4 L, bool* valid) {
#pragma clang fp contract(off)
  float cy = L.x, cx = L.y, h = L.z, w = L.w;
  float y1 = cy - 0.5f * h;
  float x1 = cx - 0.5f * w;
  float y2 = cy + 0.5f * h;
  float x2 = cx + 0.5f * w;
  *valid = ((y2 - y1) > 16.0f) && ((x2 - x1) > 16.0f);
  float4 b;
  b.x = fminf(fmaxf(y1, 0.0f), 800.0f);
  b.y = fminf(fmaxf(x1, 0.0f), 800.0f);
  b.z = fminf(fmaxf(y2, 0.0f), 800.0f);
  b.w = fminf(fmaxf(x2, 0.0f), 800.0f);
  return b;
}

__device__ __forceinline__ float box_area(const float4 b) {
#pragma clang fp contract(off)
  return (b.z - b.x) * (b.w - b.y);
}

__device__ __forceinline__ bool iou_gt_thr(const float4 a, float aa,
                                           const float4 b, float ab) {
#pragma clang fp contract(off)
  float iy = fminf(a.z, b.z) - fmaxf(a.x, b.x);
  float ix = fminf(a.w, b.w) - fmaxf(a.y, b.y);
  iy = fmaxf(iy, 0.0f);
  ix = fmaxf(ix, 0.0f);
  float inter = iy * ix;
  float uni = aa + ab - inter;
  // exact IEEE division kept: predicate must bit-match the numpy reference
  return (inter > 0.0f) && (uni > 0.0f) && ((inter / uni) > NMS_THR);
}

__device__ __forceinline__ ull wave_or64(ull v) {
  #pragma unroll
  for (int m = 1; m < 64; m <<= 1) {
    unsigned lo = __shfl_xor((unsigned)v, m, 64);
    unsigned hi = __shfl_xor((unsigned)(v >> 32), m, 64);
    v |= ((ull)hi << 32) | (ull)lo;
  }
  return v;
}

// ---------------------------------------------------------------------------
// K1: decode + clip + score; zeroes invBits (graph-replay determinism).
// ---------------------------------------------------------------------------
__global__ __launch_bounds__(256) void decode_kernel(
    const float* __restrict__ locs, const float* __restrict__ scores,
    float4* __restrict__ boxesRaw, unsigned char* __restrict__ vsRaw,
    float* __restrict__ sc, ull* __restrict__ invBits) {
  int i = blockIdx.x * 256 + threadIdx.x;
  if (i < NWORDS) invBits[i] = 0ull;
  if (i >= N) return;
  float4 L = reinterpret_cast<const float4*>(locs)[i];   // cy, cx, h, w
  bool valid;
  float4 b = decode_clip_box(L, &valid);
  boxesRaw[i] = b;
  vsRaw[i] = valid ? 1 : 0;
  sc[i] = valid ? scores[i] : -__builtin_inff();
}

// ---------------------------------------------------------------------------
// K2: partial rank counts (stable descending argsort via counting).
// j precedes i <=> s_j > s_i || (s_j == s_i && j < i).
// ---------------------------------------------------------------------------
__global__ __launch_bounds__(256) void rankpart_kernel(
    const float* __restrict__ sc, u16* __restrict__ partial) {
  int i = blockIdx.x * 256 + threadIdx.x;   // box index
  int s = blockIdx.y;                        // slice index
  float si = sc[i];
  const float4* sc4 = reinterpret_cast<const float4*>(sc + s * SLICE);
  int j0 = s * SLICE;
  int cnt = 0;
  for (int q = 0; q < SLICE / 4; ++q) {
    float4 v = sc4[q];
    int j = j0 + q * 4;
    cnt += (v.x > si) || ((v.x == si) & ((j + 0) < i));
    cnt += (v.y > si) || ((v.y == si) & ((j + 1) < i));
    cnt += (v.z > si) || ((v.z == si) & ((j + 2) < i));
    cnt += (v.w > si) || ((v.w == si) & ((j + 3) < i));
  }
  partial[s * N + i] = (u16)cnt;
}

// ---------------------------------------------------------------------------
// K3: gather into sorted order; build invalid bitmap in sorted positions.
// ---------------------------------------------------------------------------
__global__ __launch_bounds__(256) void gather_kernel(
    const u16* __restrict__ partial, const float4* __restrict__ boxesRaw,
    const unsigned char* __restrict__ vsRaw,
    float4* __restrict__ bs, float* __restrict__ area, ull* __restrict__ invBits) {
  int i = blockIdx.x * 256 + threadIdx.x;
  int r = 0;
  #pragma unroll
  for (int s = 0; s < SPLIT; ++s) r += (int)partial[s * N + i];
  float4 b = boxesRaw[i];
  bs[r] = b;
  area[r] = box_area(b);
  if (!vsRaw[i]) atomicOr(&invBits[r >> 6], 1ull << (r & 63));
}

// ---------------------------------------------------------------------------
// K4: suppression bitmask, TRANSPOSED layout maskT[cb*N + row].
// Block (cbq, rb): 4 column-words cbq*4..+3 vs row-word rb; 256 threads.
// Writes are 512B-contiguous per wave.  Upper triangle + diagonal only.
// ---------------------------------------------------------------------------
__global__ __launch_bounds__(256) void mask_kernel(
    const float4* __restrict__ bs, const float* __restrict__ area,
    ull* __restrict__ maskT) {
  int cbq = blockIdx.x;              // [0,32)
  int rb  = blockIdx.y;              // [0,128)
  if (cbq * 4 + 3 < rb) return;      // whole block strictly below diagonal
  int t = threadIdx.x;
  int lane = t & 63;
  int cq = t >> 6;                   // [0,4)
  int cb = cbq * 4 + cq;
  __shared__ float4 sb[4][64];
  __shared__ float  sa[4][64];
  int j0 = cb * 64;
  sb[cq][lane] = bs[j0 + lane];
  sa[cq][lane] = area[j0 + lane];
  int i = rb * 64 + lane;
  float4 r = bs[i];
  float ai = area[i];
  __syncthreads();
  if (cb < rb) return;               // this column-word below diagonal
  ull bits = 0;
  for (int c = 0; c < 64; ++c) {
    if ((j0 + c) > i && iou_gt_thr(r, ai, sb[cq][c], sa[cq][c])) bits |= 1ull << c;
  }
  maskT[(size_t)cb * N + i] = bits;
}

// ---------------------------------------------------------------------------
// K5: greedy scan, 256 boxes (4 words) per sequential iteration.
//  Phase A (wave 0): resolve 4 sub-words in LDS; cross-sub-word suppression
//    via shfl OR-butterfly; kept set recorded as bitmap sKept[word].
//  Gather phase (all 256): pull next group's suppression = OR over all kept
//    rows of maskT[wq][r] (affine coalesced loads, masked by sKept bitmap),
//    plus prefetch next group's 8 KiB diag block.
// ---------------------------------------------------------------------------
__global__ __launch_bounds__(256) void scan_kernel(
    const ull* __restrict__ maskT, const ull* __restrict__ invBits,
    const float4* __restrict__ bs, float* __restrict__ out) {
  __shared__ ull sRemv[NWORDS];
  __shared__ ull sKept[NWORDS];
  __shared__ ull sDiag[GBOX][GROUP];     // 8 KiB: [row-in-group][word-in-group]
  __shared__ int sKeptList[NPOST];       // 8 KiB
  __shared__ int sKeptBase;
  __shared__ int sStop;
  int tid = threadIdx.x;

  if (tid == 0) { sKeptBase = 0; sStop = 0; }
  if (tid < NWORDS) { sRemv[tid] = invBits[tid]; sKept[tid] = 0ull; }
  #pragma unroll
  for (int j = 0; j < GROUP; ++j)        // prefetch group 0 diag (coalesced)
    sDiag[tid][j] = maskT[(size_t)j * N + tid];
  __syncthreads();

  for (int gt = 0; gt < NGROUPS; ++gt) {
    int w0 = gt * GROUP;
    // ---- Phase A: wave 0 resolves the group's 4 words sequentially
    if (tid < 64) {
      int lane = tid;
      int base = sKeptBase;
      for (int q = 0; q < GROUP; ++q) {
        int wq = w0 + q;
        ull dgq = sDiag[q * 64 + lane][q];     // own diag word (bits > lane)
        ull avail = ~sRemv[wq];                // uniform (broadcast read)
        ull kept;
        ull conflict = __ballot(((dgq & avail) != 0ull) && ((avail >> lane) & 1ull));
        if (conflict == 0ull) {
          kept = avail;                        // no internal suppression
        } else {
          ull dgT = 0ull;                      // transpose: my suppressors
          #pragma unroll
          for (int c = 0; c < 64; ++c) {
            ull tb = __ballot((dgq >> c) & 1ull);
            if (lane == c) dgT = tb;
          }
          kept = avail;
          while (true) {                       // fixpoint == greedy
            bool sup = (dgT & kept) != 0ull;
            ull kn = avail & ~__ballot(sup);
            if (kn == kept) break;
            kept = kn;
          }
        }
        if (lane == 0) sKept[wq] = kept;
        if ((kept >> lane) & 1ull) {
          int rank = base + (int)__popcll(kept & ((1ull << lane) - 1ull));
          if (rank < NPOST) sKeptList[rank] = wq * 64 + lane;
        }
        base += (int)__popcll(kept);
        if (base >= NPOST) break;              // later keeps would rank >=2000
        // suppress later sub-words of this group (in-LDS, butterfly OR)
        for (int q2 = q + 1; q2 < GROUP; ++q2) {
          ull contrib = ((kept >> lane) & 1ull) ? sDiag[q * 64 + lane][q2] : 0ull;
          contrib = wave_or64(contrib);
          if (lane == 0) sRemv[w0 + q2] |= contrib;  // same-wave LDS order OK
        }
      }
      if (lane == 0) { sKeptBase = base; if (base >= NPOST) sStop = 1; }
    }
    __syncthreads();
    if (sStop) break;
    if (gt + 1 < NGROUPS) {
      // ---- Gather next group's suppression (wave q handles word w0+4+q)
      int q = tid >> 6, lane = tid & 63;
      int wq = (gt + 1) * GROUP + q;
      const ull* mw = maskT + (size_t)wq * N;
      int nj = (gt + 1) * GROUP;               // rows 0..(gt+1)*256-1
      ull acc = 0;
      for (int j = 0; j < nj; j += 4) {        // affine, coalesced, 4-deep
        ull v0 = mw[(j + 0) * 64 + lane];
        ull v1 = mw[(j + 1) * 64 + lane];
        ull v2 = mw[(j + 2) * 64 + lane];
        ull v3 = mw[(j + 3) * 64 + lane];
        ull k0 = sKept[j + 0], k1 = sKept[j + 1];
        ull k2 = sKept[j + 2], k3 = sKept[j + 3];
        acc |= (((k0 >> lane) & 1ull) ? v0 : 0ull) |
               (((k1 >> lane) & 1ull) ? v1 : 0ull) |
               (((k2 >> lane) & 1ull) ? v2 : 0ull) |
               (((k3 >> lane) & 1ull) ? v3 : 0ull);
      }
      acc = wave_or64(acc);
      if (lane == 0) sRemv[wq] |= acc;
      // ---- prefetch next group's diag block (coalesced 2 KiB per word)
      int rg = (gt + 1) * GBOX + tid;
      #pragma unroll
      for (int j = 0; j < GROUP; ++j)
        sDiag[tid][j] = maskT[(size_t)((gt + 1) * GROUP + j) * N + rg];
    }
    __syncthreads();
  }

  __syncthreads();
  int total = sKeptBase;
  if (total > NPOST) total = NPOST;
  for (int r = tid; r < NPOST; r += 256) {
    float4 v = make_float4(0.0f, 0.0f, 0.0f, 0.0f);
    if (r < total) v = bs[sKeptList[r]];
    reinterpret_cast<float4*>(out)[r] = v;
  }
}

// ---------------------------------------------------------------------------
extern "C" void kernel_launch(void* const* d_in, const int* in_sizes, int n_in,
                              void* d_out, int out_size, void* d_ws, size_t ws_size,
                              hipStream_t stream) {
  const float* locs   = (const float*)d_in[0];   // (8192,4) cy,cx,h,w
  const float* scores = (const float*)d_in[1];   // (8192,)

  char* ws = (char*)d_ws;
  float*         sc       = (float*)(ws + 0);
  float4*        boxesRaw = (float4*)(ws + 32768);
  unsigned char* vsRaw    = (unsigned char*)(ws + 163840);
  float4*        bs       = (float4*)(ws + 172032);
  float*         area     = (float*)(ws + 303104);
  ull*           invBits  = (ull*)(ws + 335872);
  u16*           partial  = (u16*)(ws + 336896);
  ull*           maskT    = (ull*)(ws + 524288);

  decode_kernel<<<N / 256, 256, 0, stream>>>(locs, scores, boxesRaw, vsRaw, sc, invBits);
  rankpart_kernel<<<dim3(N / 256, SPLIT), 256, 0, stream>>>(sc, partial);
  gather_kernel<<<N / 256, 256, 0, stream>>>(partial, boxesRaw, vsRaw, bs, area, invBits);
  mask_kernel<<<dim3(NWORDS / 4, NWORDS), 256, 0, stream>>>(bs, area, maskT);
  scan_kernel<<<1, 256, 0, stream>>>(maskT, invBits, bs, (float*)d_out);
}

// Round 8
// 154.613 us; speedup vs baseline: 5.1610x; 1.0798x over previous
//
#include <hip/hip_runtime.h>
#include <cstdint>
#include <cstddef>

typedef unsigned long long ull;
typedef unsigned short u16;

#define N 8192
#define NWORDS 128          // 8192 / 64
#define NPOST 2000
#define NMS_THR 0.7f
#define SPLIT 8
#define SLICE (N / SPLIT)   // 1024
#define GROUP 4             // words per sequential group
#define GBOX 256            // boxes per group
#define MASKW 48            // words with precomputed mask (stop ~word 34)
#define NGMASK (MASKW / GROUP)     // 12 masked groups

// All kernels <=256 threads; scan LDS ~31.6KB (64KB class failed in r2/3).

// ---------------- ws layout ----------------
// 0      : sc        f32[8192]      32 KiB  (score, -inf if invalid)
// 32768  : boxesRaw  float4[8192]   128 KiB
// 163840 : vsRaw     u8[8192]       8 KiB
// 172032 : bs        float4[8192]   128 KiB (sorted clipped boxes)
// 303104 : area      f32[8192]      32 KiB  (sorted areas)
// 335872 : invBits   ull[128]       1 KiB   (sorted-order invalid bitmap)
// 336896 : partial   u16[8*8192]    128 KiB (rank partial counts)
// 524288 : maskT     ull[128*8192]  8 MiB   TRANSPOSED maskT[cb*N+row]; only
//                                           cols 0..MASKW-1, upper tri written

// ---------------------------------------------------------------------------
__device__ __forceinline__ float4 decode_clip_box(const float4 L, bool* valid) {
#pragma clang fp contract(off)
  float cy = L.x, cx = L.y, h = L.z, w = L.w;
  float y1 = cy - 0.5f * h;
  float x1 = cx - 0.5f * w;
  float y2 = cy + 0.5f * h;
  float x2 = cx + 0.5f * w;
  *valid = ((y2 - y1) > 16.0f) && ((x2 - x1) > 16.0f);
  float4 b;
  b.x = fminf(fmaxf(y1, 0.0f), 800.0f);
  b.y = fminf(fmaxf(x1, 0.0f), 800.0f);
  b.z = fminf(fmaxf(y2, 0.0f), 800.0f);
  b.w = fminf(fmaxf(x2, 0.0f), 800.0f);
  return b;
}

__device__ __forceinline__ float box_area(const float4 b) {
#pragma clang fp contract(off)
  return (b.z - b.x) * (b.w - b.y);
}

__device__ __forceinline__ bool iou_gt_thr(const float4 a, float aa,
                                           const float4 b, float ab) {
#pragma clang fp contract(off)
  float iy = fminf(a.z, b.z) - fmaxf(a.x, b.x);
  float ix = fminf(a.w, b.w) - fmaxf(a.y, b.y);
  iy = fmaxf(iy, 0.0f);
  ix = fmaxf(ix, 0.0f);
  float inter = iy * ix;
  float uni = aa + ab - inter;
  // exact IEEE division: predicate must bit-match the numpy reference
  return (inter > 0.0f) && (uni > 0.0f) && ((inter / uni) > NMS_THR);
}

__device__ __forceinline__ ull wave_or64(ull v) {
  #pragma unroll
  for (int m = 1; m < 64; m <<= 1) {
    unsigned lo = __shfl_xor((unsigned)v, m, 64);
    unsigned hi = __shfl_xor((unsigned)(v >> 32), m, 64);
    v |= ((ull)hi << 32) | (ull)lo;
  }
  return v;
}

// Greedy within-word resolve.  dg: rows this lane suppresses (bits > lane).
// Fast path: no internal conflict among avail -> kept = avail.  Slow path:
// ballot bit-transpose + fixpoint kept <- avail & ~N+(kept) (== greedy by
// prefix-stabilization).
__device__ __forceinline__ ull resolve_word(ull dg, ull avail, int lane) {
  ull conflict = __ballot(((dg & avail) != 0ull) && ((avail >> lane) & 1ull));
  if (conflict == 0ull) return avail;
  ull dgT = 0ull;
  #pragma unroll
  for (int c = 0; c < 64; ++c) {
    ull tb = __ballot((dg >> c) & 1ull);
    if (lane == c) dgT = tb;
  }
  ull kept = avail;
  while (true) {
    bool sup = (dgT & kept) != 0ull;
    ull kn = avail & ~__ballot(sup);
    if (kn == kept) break;
    kept = kn;
  }
  return kept;
}

// ---------------------------------------------------------------------------
// K1: decode + clip + score; zeroes invBits (graph-replay determinism).
// ---------------------------------------------------------------------------
__global__ __launch_bounds__(256) void decode_kernel(
    const float* __restrict__ locs, const float* __restrict__ scores,
    float4* __restrict__ boxesRaw, unsigned char* __restrict__ vsRaw,
    float* __restrict__ sc, ull* __restrict__ invBits) {
  int i = blockIdx.x * 256 + threadIdx.x;
  if (i < NWORDS) invBits[i] = 0ull;
  if (i >= N) return;
  float4 L = reinterpret_cast<const float4*>(locs)[i];   // cy, cx, h, w
  bool valid;
  float4 b = decode_clip_box(L, &valid);
  boxesRaw[i] = b;
  vsRaw[i] = valid ? 1 : 0;
  sc[i] = valid ? scores[i] : -__builtin_inff();
}

// ---------------------------------------------------------------------------
// K2: partial rank counts (stable descending argsort via counting).
// j precedes i <=> s_j > s_i || (s_j == s_i && j < i).
// ---------------------------------------------------------------------------
__global__ __launch_bounds__(256) void rankpart_kernel(
    const float* __restrict__ sc, u16* __restrict__ partial) {
  int i = blockIdx.x * 256 + threadIdx.x;   // box index
  int s = blockIdx.y;                        // slice index
  float si = sc[i];
  const float4* sc4 = reinterpret_cast<const float4*>(sc + s * SLICE);
  int j0 = s * SLICE;
  int cnt = 0;
  for (int q = 0; q < SLICE / 4; ++q) {
    float4 v = sc4[q];
    int j = j0 + q * 4;
    cnt += (v.x > si) || ((v.x == si) & ((j + 0) < i));
    cnt += (v.y > si) || ((v.y == si) & ((j + 1) < i));
    cnt += (v.z > si) || ((v.z == si) & ((j + 2) < i));
    cnt += (v.w > si) || ((v.w == si) & ((j + 3) < i));
  }
  partial[s * N + i] = (u16)cnt;
}

// ---------------------------------------------------------------------------
// K3: gather into sorted order; invalid bitmap in sorted positions.
// ---------------------------------------------------------------------------
__global__ __launch_bounds__(256) void gather_kernel(
    const u16* __restrict__ partial, const float4* __restrict__ boxesRaw,
    const unsigned char* __restrict__ vsRaw,
    float4* __restrict__ bs, float* __restrict__ area, ull* __restrict__ invBits) {
  int i = blockIdx.x * 256 + threadIdx.x;
  int r = 0;
  #pragma unroll
  for (int s = 0; s < SPLIT; ++s) r += (int)partial[s * N + i];
  float4 b = boxesRaw[i];
  bs[r] = b;
  area[r] = box_area(b);
  if (!vsRaw[i]) atomicOr(&invBits[r >> 6], 1ull << (r & 63));
}

// ---------------------------------------------------------------------------
// K4: suppression bitmask, TRANSPOSED maskT[cb*N+row]; columns 0..MASKW-1,
// upper triangle + diagonal only.
// ---------------------------------------------------------------------------
__global__ __launch_bounds__(256) void mask_kernel(
    const float4* __restrict__ bs, const float* __restrict__ area,
    ull* __restrict__ maskT) {
  int cbq = blockIdx.x;              // [0, MASKW/4)
  int rb  = blockIdx.y;              // [0, MASKW)
  if (cbq * 4 + 3 < rb) return;      // whole block strictly below diagonal
  int t = threadIdx.x;
  int lane = t & 63;
  int cq = t >> 6;                   // [0,4)
  int cb = cbq * 4 + cq;
  __shared__ float4 sb[4][64];
  __shared__ float  sa[4][64];
  int j0 = cb * 64;
  sb[cq][lane] = bs[j0 + lane];
  sa[cq][lane] = area[j0 + lane];
  int i = rb * 64 + lane;
  float4 r = bs[i];
  float ai = area[i];
  __syncthreads();
  if (cb < rb) return;               // this column-word below diagonal
  ull bits = 0;
  for (int c = 0; c < 64; ++c) {
    if ((j0 + c) > i && iou_gt_thr(r, ai, sb[cq][c], sa[cq][c])) bits |= 1ull << c;
  }
  maskT[(size_t)cb * N + i] = bits;
}

// ---------------------------------------------------------------------------
// K5: greedy scan.
//  Masked phase (groups 0..NGMASK-1), per group:
//   Phase A: wave 0 resolves 4 sub-words (LDS/VALU only).  Concurrently,
//     waves 1-3: (a) gather suppression for group g+1 from kept rows of
//     groups <= g-1 (global, latency hidden under Phase A), (b) speculative
//     prefetch sBlk = maskT[words g+1][rows g] and next diag block.
//   Phase B: merge (a)+(b, bitmap-selected in LDS) into sRemv[group g+1].
//  Fallback phase (words >= MASKW, only if not stopped): on-the-fly IoU.
// ---------------------------------------------------------------------------
__global__ __launch_bounds__(256) void scan_kernel(
    const ull* __restrict__ maskT, const ull* __restrict__ invBits,
    const float4* __restrict__ bs, const float* __restrict__ area,
    float* __restrict__ out) {
  __shared__ ull sDiag[2][GBOX][GROUP];  // 16 KiB  [row-in-group][word-in-grp]
  __shared__ ull sBlk[GBOX][GROUP];      // 8 KiB   rows of g vs words of g+1
  __shared__ ull sRemv[NWORDS];          // 1 KiB
  __shared__ ull sKept[NWORDS];          // 1 KiB
  __shared__ ull sPre[GROUP];
  __shared__ u16 sKeptList[NPOST];       // 4000 B
  __shared__ float4 sWB[64];             // fallback staging
  __shared__ float  sWA[64];
  __shared__ ull sSupW;
  __shared__ int sKeptBase;
  __shared__ int sStop;
  int tid = threadIdx.x;

  if (tid == 0) { sKeptBase = 0; sStop = 0; }
  if (tid < GROUP) sPre[tid] = 0ull;
  if (tid < NWORDS) { sRemv[tid] = invBits[tid]; sKept[tid] = 0ull; }
  #pragma unroll
  for (int j = 0; j < GROUP; ++j)        // diag block of group 0 (coalesced)
    sDiag[0][tid][j] = maskT[(size_t)j * N + tid];
  __syncthreads();

  // ---------------- masked phase ----------------
  for (int gt = 0; gt < NGMASK; ++gt) {
    int w0 = gt * GROUP;
    int buf = gt & 1;
    if (tid < 64) {
      // ---- Phase A: wave 0, pure LDS/VALU
      int lane = tid;
      int base = sKeptBase;
      for (int q = 0; q < GROUP; ++q) {
        int wq = w0 + q;
        ull dgq = sDiag[buf][q * 64 + lane][q];
        ull avail = ~sRemv[wq];                        // uniform
        ull kept = resolve_word(dgq, avail, lane);
        if (lane == 0) sKept[wq] = kept;
        if ((kept >> lane) & 1ull) {
          int rank = base + (int)__popcll(kept & ((1ull << lane) - 1ull));
          if (rank < NPOST) sKeptList[rank] = (u16)(wq * 64 + lane);
        }
        base += (int)__popcll(kept);
        if (base >= NPOST) break;        // later keeps would rank >= 2000
        for (int q2 = q + 1; q2 < GROUP; ++q2) {       // in-group suppression
          ull contrib = ((kept >> lane) & 1ull) ? sDiag[buf][q * 64 + lane][q2]
                                                : 0ull;
          contrib = wave_or64(contrib);
          if (lane == 0) sRemv[w0 + q2] |= contrib;    // same-wave order OK
        }
      }
      if (lane == 0) { sKeptBase = base; if (base >= NPOST) sStop = 1; }
    } else if (gt + 1 < NGMASK) {
      // ---- waves 1-3: gather + speculative prefetch for group gt+1
      int t2 = tid - 64;                 // 0..191
      int wbase = (gt + 1) * GROUP;
      int nr = gt * GBOX;                // rows of groups 0..gt-1
      for (int j = 0; j < GROUP; ++j) {
        const ull* mw = maskT + (size_t)(wbase + j) * N;
        ull acc = 0;
        for (int r0 = 0; r0 < nr; r0 += 4 * 192) {     // 4-deep, shfl-uniform
          int ra = r0 + t2;
          int rb2 = ra + 192, rc = ra + 384, rd = ra + 576;
          ull m0 = (ra  < nr) ? mw[ra]  : 0ull;
          ull m1 = (rb2 < nr) ? mw[rb2] : 0ull;
          ull m2 = (rc  < nr) ? mw[rc]  : 0ull;
          ull m3 = (rd  < nr) ? mw[rd]  : 0ull;
          acc |= (((sKept[(ra  & 8191) >> 6] >> (ra  & 63)) & 1ull) ? m0 : 0ull);
          acc |= (((sKept[(rb2 & 8191) >> 6] >> (rb2 & 63)) & 1ull) ? m1 : 0ull);
          acc |= (((sKept[(rc  & 8191) >> 6] >> (rc  & 63)) & 1ull) ? m2 : 0ull);
          acc |= (((sKept[(rd  & 8191) >> 6] >> (rd  & 63)) & 1ull) ? m3 : 0ull);
        }
        acc = wave_or64(acc);
        if ((t2 & 63) == 0 && acc) atomicOr(&sPre[j], acc);
        // speculative: rows of group gt vs word wbase+j  (read Phase B)
        sBlk[t2][j] = mw[nr + t2];
        if (t2 < 64) sBlk[t2 + 192][j] = mw[nr + t2 + 192];
        // next diag block: rows of group gt+1 vs word wbase+j
        sDiag[buf ^ 1][t2][j] = mw[(gt + 1) * GBOX + t2];
        if (t2 < 64) sDiag[buf ^ 1][t2 + 192][j] = mw[(gt + 1) * GBOX + t2 + 192];
      }
    }
    __syncthreads();
    if (sStop) break;
    if (gt + 1 < NGMASK) {
      // ---- Phase B: merge group gt's own contribution (LDS) + sPre
      int j = tid >> 6, lane = tid & 63;
      ull acc = 0;
      #pragma unroll
      for (int q = 0; q < GROUP; ++q)
        acc |= (((sKept[w0 + q] >> lane) & 1ull) ? sBlk[q * 64 + lane][j] : 0ull);
      acc = wave_or64(acc);
      if (lane == 0) {
        sRemv[(gt + 1) * GROUP + j] |= acc | sPre[j];
        sPre[j] = 0ull;
      }
    }
    __syncthreads();
  }

  // ---------------- fallback phase (correctness only; not hit by bench) ----
  if (!sStop) {
    for (int w = MASKW; w < NWORDS; ++w) {
      if (tid < 64) { sWB[tid] = bs[w * 64 + tid]; sWA[tid] = area[w * 64 + tid]; }
      if (tid == 0) sSupW = sRemv[w];
      __syncthreads();
      int nk = sKeptBase;
      int c = tid & 63;
      for (int k0 = tid >> 6; k0 < nk; k0 += 4) {      // wave per kept box
        int ki = sKeptList[k0];
        float4 kb = bs[ki];                            // broadcast load
        bool s = iou_gt_thr(kb, area[ki], sWB[c], sWA[c]);
        ull bits = __ballot(s);
        if (c == 0 && bits) atomicOr(&sSupW, bits);
      }
      __syncthreads();
      if (tid < 64) {
        int lane = tid;
        float4 bm = sWB[lane];
        float am = sWA[lane];
        ull dg = 0;
        for (int cc = lane + 1; cc < 64; ++cc)
          if (iou_gt_thr(bm, am, sWB[cc], sWA[cc])) dg |= 1ull << cc;
        ull avail = ~sSupW;
        ull kept = resolve_word(dg, avail, lane);
        int base = sKeptBase;
        if ((kept >> lane) & 1ull) {
          int rank = base + (int)__popcll(kept & ((1ull << lane) - 1ull));
          if (rank < NPOST) sKeptList[rank] = (u16)(w * 64 + lane);
        }
        if (lane == 0) {
          int nb = base + (int)__popcll(kept);
          sKeptBase = nb;
          if (nb >= NPOST) sStop = 1;
        }
      }
      __syncthreads();
      if (sStop) break;
    }
  }

  __syncthreads();
  int total = sKeptBase;
  if (total > NPOST) total = NPOST;
  for (int r = tid; r < NPOST; r += 256) {
    float4 v = make_float4(0.0f, 0.0f, 0.0f, 0.0f);
    if (r < total) v = bs[sKeptList[r]];
    reinterpret_cast<float4*>(out)[r] = v;
  }
}

// ---------------------------------------------------------------------------
extern "C" void kernel_launch(void* const* d_in, const int* in_sizes, int n_in,
                              void* d_out, int out_size, void* d_ws, size_t ws_size,
                              hipStream_t stream) {
  const float* locs   = (const float*)d_in[0];   // (8192,4) cy,cx,h,w
  const float* scores = (const float*)d_in[1];   // (8192,)

  char* ws = (char*)d_ws;
  float*         sc       = (float*)(ws + 0);
  float4*        boxesRaw = (float4*)(ws + 32768);
  unsigned char* vsRaw    = (unsigned char*)(ws + 163840);
  float4*        bs       = (float4*)(ws + 172032);
  float*         area     = (float*)(ws + 303104);
  ull*           invBits  = (ull*)(ws + 335872);
  u16*           partial  = (u16*)(ws + 336896);
  ull*           maskT    = (ull*)(ws + 524288);

  decode_kernel<<<N / 256, 256, 0, stream>>>(locs, scores, boxesRaw, vsRaw, sc, invBits);
  rankpart_kernel<<<dim3(N / 256, SPLIT), 256, 0, stream>>>(sc, partial);
  gather_kernel<<<N / 256, 256, 0, stream>>>(partial, boxesRaw, vsRaw, bs, area, invBits);
  mask_kernel<<<dim3(MASKW / 4, MASKW), 256, 0, stream>>>(bs, area, maskT);
  scan_kernel<<<1, 256, 0, stream>>>(maskT, invBits, bs, area, (float*)d_out);
}

// Round 9
// 89.709 us; speedup vs baseline: 8.8949x; 1.7235x over previous
//
#include <hip/hip_runtime.h>
#include <cstdint>
#include <cstddef>

typedef unsigned long long ull;
typedef unsigned short u16;

#define N 8192
#define NWORDS 128          // 8192 / 64
#define NPOST 2000
#define NMS_THR 0.7f
#define SPLIT 8
#define SLICE (N / SPLIT)   // 1024
#define MASKW 48            // words covered by sparse conflict pairs (stop ~34)
#define CCAP 128            // cross-word pair cap per word
#define ICAP 16             // in-word pair cap per word

// All kernels <=256 threads; scan LDS ~36KB (32KB proven in r8; 64KB+1024thr
// failed silently in r2/3).

// ---------------- ws layout ----------------
// 0      : partial  u16[8*8192]   128 KiB (rank partial counts)
// 131072 : bs       float4[8192]  128 KiB (sorted clipped boxes)
// 262144 : area     f32[8192]     32 KiB  (sorted areas)
// 294912 : invBits  ull[128]      1 KiB   (sorted-order invalid bitmap)
// 295936 : ctrl     i32[64]       256 B   ([0..47] crossCnt, [48] overflowFlag)
// 296192 : inCnt    i32[64]       256 B   ([0..47] in-word pair counts)
// 296448 : crossBuf u32[48*128]   24 KiB  ((jl<<16)|i per pair)
// 321024 : inBuf    u32[48*16]    3 KiB   ((jl<<8)|il per pair)

// ---------------------------------------------------------------------------
__device__ __forceinline__ float4 decode_clip_box(const float4 L, bool* valid) {
#pragma clang fp contract(off)
  float cy = L.x, cx = L.y, h = L.z, w = L.w;
  float y1 = cy - 0.5f * h;
  float x1 = cx - 0.5f * w;
  float y2 = cy + 0.5f * h;
  float x2 = cx + 0.5f * w;
  *valid = ((y2 - y1) > 16.0f) && ((x2 - x1) > 16.0f);
  float4 b;
  b.x = fminf(fmaxf(y1, 0.0f), 800.0f);
  b.y = fminf(fmaxf(x1, 0.0f), 800.0f);
  b.z = fminf(fmaxf(y2, 0.0f), 800.0f);
  b.w = fminf(fmaxf(x2, 0.0f), 800.0f);
  return b;
}

__device__ __forceinline__ float box_area(const float4 b) {
#pragma clang fp contract(off)
  return (b.z - b.x) * (b.w - b.y);
}

__device__ __forceinline__ bool iou_gt_thr(const float4 a, float aa,
                                           const float4 b, float ab) {
#pragma clang fp contract(off)
  float iy = fminf(a.z, b.z) - fmaxf(a.x, b.x);
  float ix = fminf(a.w, b.w) - fmaxf(a.y, b.y);
  iy = fmaxf(iy, 0.0f);
  ix = fmaxf(ix, 0.0f);
  float inter = iy * ix;
  float uni = aa + ab - inter;
  // exact IEEE division: predicate must bit-match the numpy reference
  return (inter > 0.0f) && (uni > 0.0f) && ((inter / uni) > NMS_THR);
}

__device__ __forceinline__ ull wave_or64(ull v) {
  #pragma unroll
  for (int m = 1; m < 64; m <<= 1) {
    unsigned lo = __shfl_xor((unsigned)v, m, 64);
    unsigned hi = __shfl_xor((unsigned)(v >> 32), m, 64);
    v |= ((ull)hi << 32) | (ull)lo;
  }
  return v;
}

// Greedy within-word resolve from "who-I-suppress" masks (used by fallback).
__device__ __forceinline__ ull resolve_word(ull dg, ull avail, int lane) {
  ull conflict = __ballot(((dg & avail) != 0ull) && ((avail >> lane) & 1ull));
  if (conflict == 0ull) return avail;
  ull dgT = 0ull;
  #pragma unroll
  for (int c = 0; c < 64; ++c) {
    ull tb = __ballot((dg >> c) & 1ull);
    if (lane == c) dgT = tb;
  }
  ull kept = avail;
  while (true) {                 // fixpoint == greedy (prefix-stabilization)
    bool sup = (dgT & kept) != 0ull;
    ull kn = avail & ~__ballot(sup);
    if (kn == kept) break;
    kept = kn;
  }
  return kept;
}

// ---------------------------------------------------------------------------
// K1: partial rank counts; decodes its slice's scores into LDS (no decode
// kernel needed).  Block (0,0) zeroes invBits/ctrl/inCnt (runs before gather
// and pairs by stream order).
// ---------------------------------------------------------------------------
__global__ __launch_bounds__(256) void rankpart_kernel(
    const float* __restrict__ locs, const float* __restrict__ scores,
    u16* __restrict__ partial, ull* __restrict__ invBits,
    int* __restrict__ ctrl, int* __restrict__ inCnt) {
  __shared__ float ssc[SLICE];         // 4 KiB
  int bx = blockIdx.x, s = blockIdx.y;
  int tid = threadIdx.x;
  if (bx == 0 && s == 0) {
    if (tid < NWORDS) invBits[tid] = 0ull;
    else if (tid < NWORDS + 64) ctrl[tid - NWORDS] = 0;
    else if (tid < NWORDS + 64 + 48) inCnt[tid - NWORDS - 64] = 0;
  }
  const float4* locs4 = (const float4*)locs;
  for (int k = tid; k < SLICE; k += 256) {
    int j = s * SLICE + k;
    bool v; (void)decode_clip_box(locs4[j], &v);
    ssc[k] = v ? scores[j] : -__builtin_inff();
  }
  int i = bx * 256 + tid;
  bool vi; (void)decode_clip_box(locs4[i], &vi);
  float si = vi ? scores[i] : -__builtin_inff();
  __syncthreads();
  // j precedes i <=> s_j > s_i || (s_j == s_i && j < i)  (stable descending)
  int j0 = s * SLICE;
  int cnt = 0;
  const float4* s4 = (const float4*)ssc;
  for (int q = 0; q < SLICE / 4; ++q) {
    float4 v = s4[q];                  // LDS broadcast (uniform q)
    int j = j0 + q * 4;
    cnt += (v.x > si) || ((v.x == si) & ((j + 0) < i));
    cnt += (v.y > si) || ((v.y == si) & ((j + 1) < i));
    cnt += (v.z > si) || ((v.z == si) & ((j + 2) < i));
    cnt += (v.w > si) || ((v.w == si) & ((j + 3) < i));
  }
  partial[s * N + i] = (u16)cnt;
}

// ---------------------------------------------------------------------------
// K2: gather into sorted order (re-decodes own box); invalid bitmap.
// ---------------------------------------------------------------------------
__global__ __launch_bounds__(256) void gather_kernel(
    const float* __restrict__ locs, const u16* __restrict__ partial,
    float4* __restrict__ bs, float* __restrict__ area,
    ull* __restrict__ invBits) {
  int i = blockIdx.x * 256 + threadIdx.x;
  int r = 0;
  #pragma unroll
  for (int s = 0; s < SPLIT; ++s) r += (int)partial[s * N + i];
  bool v;
  float4 b = decode_clip_box(((const float4*)locs)[i], &v);
  bs[r] = b;
  area[r] = box_area(b);
  if (!v) atomicOr(&invBits[r >> 6], 1ull << (r & 63));
}

// ---------------------------------------------------------------------------
// K3: sparse conflict pairs among first MASKW*64 sorted boxes.
// Pair (i<j), both valid, IoU>0.7.  Bucketed by word(j); in-word pairs
// separately.  Overflow of any cap -> ctrl[48]=1 (scan falls back dense).
// ---------------------------------------------------------------------------
__global__ __launch_bounds__(256) void pairs_kernel(
    const float4* __restrict__ bs, const float* __restrict__ area,
    const ull* __restrict__ invBits,
    int* __restrict__ ctrl, int* __restrict__ inCnt,
    unsigned* __restrict__ crossBuf, unsigned* __restrict__ inBuf) {
  int cbq = blockIdx.x;                // [0, MASKW/4)
  int rb  = blockIdx.y;                // [0, MASKW)
  if (cbq * 4 + 3 < rb) return;        // whole block strictly below diagonal
  int t = threadIdx.x;
  int lane = t & 63;
  int cq = t >> 6;
  int cb = cbq * 4 + cq;
  __shared__ float4 sb[4][64];
  __shared__ float  sa[4][64];
  int j0 = cb * 64;
  sb[cq][lane] = bs[j0 + lane];
  sa[cq][lane] = area[j0 + lane];
  int i = rb * 64 + lane;
  float4 r = bs[i];
  float ai = area[i];
  bool vi = !((invBits[rb] >> lane) & 1ull);
  ull invC = invBits[cb];
  __syncthreads();
  if (cb < rb || !vi) return;
  ull bits = 0;
  for (int c = 0; c < 64; ++c) {
    if ((j0 + c) > i && iou_gt_thr(r, ai, sb[cq][c], sa[cq][c])) bits |= 1ull << c;
  }
  bits &= ~invC;                        // invalid j never kept anyway
  int n = (int)__popcll(bits);
  if (!n) return;
  if (cb == rb) {                       // in-word pairs
    int base = atomicAdd(&inCnt[cb], n);
    if (base + n > ICAP) { ctrl[48] = 1; return; }
    int k = base;
    while (bits) {
      int c = (int)__builtin_ctzll(bits); bits &= bits - 1;
      inBuf[cb * ICAP + k++] = ((unsigned)c << 8) | (unsigned)lane;
    }
  } else {                              // cross-word pairs
    int base = atomicAdd(&ctrl[cb], n);
    if (base + n > CCAP) { ctrl[48] = 1; return; }
    int k = base;
    while (bits) {
      int c = (int)__builtin_ctzll(bits); bits &= bits - 1;
      crossBuf[cb * CCAP + k++] = ((unsigned)c << 16) | (unsigned)i;
    }
  }
}

// ---------------------------------------------------------------------------
// K4: greedy scan over sparse pairs — pure LDS/VALU critical path.
// Per word: lane-parallel cross-pair check vs kept bitmap (+6-shfl OR),
// in-word dgT + ballot fixpoint, bookkeeping.  Early stop at 2000.
// Fallback (overflow: from word 0; else from MASKW): on-the-fly IoU, slow
// but correct; not taken for the bench input.
// ---------------------------------------------------------------------------
__global__ __launch_bounds__(256) void scan_kernel(
    const ull* __restrict__ invBits, const int* __restrict__ ctrl,
    const int* __restrict__ inCnt, const unsigned* __restrict__ crossBuf,
    const unsigned* __restrict__ inBuf,
    const float4* __restrict__ bs, const float* __restrict__ area,
    float* __restrict__ out) {
  __shared__ unsigned sCross[MASKW][CCAP];   // 24 KiB
  __shared__ unsigned sIn[MASKW][ICAP];      // 3 KiB
  __shared__ int sCCnt[MASKW];
  __shared__ int sICnt[MASKW];
  __shared__ ull sKeptBits[NWORDS];          // 1 KiB
  __shared__ ull sRemv[NWORDS];              // 1 KiB (invalids; fallback state)
  __shared__ u16 sKeptList[NPOST];           // 4000 B
  __shared__ float4 sWB[64];                 // fallback staging
  __shared__ float  sWA[64];
  __shared__ ull sSupW;
  __shared__ int sKeptBase, sStop, sOver;
  int tid = threadIdx.x;

  if (tid < MASKW) { sCCnt[tid] = ctrl[tid]; sICnt[tid] = inCnt[tid]; }
  if (tid == 255) sOver = ctrl[48];
  if (tid == 254) sKeptBase = 0;
  if (tid == 253) sStop = 0;
  if (tid < NWORDS) { sRemv[tid] = invBits[tid]; sKeptBits[tid] = 0ull; }
  for (int k = tid; k < MASKW * CCAP; k += 256)
    ((unsigned*)sCross)[k] = crossBuf[k];
  for (int k = tid; k < MASKW * ICAP; k += 256)
    ((unsigned*)sIn)[k] = inBuf[k];
  __syncthreads();

  // ---------------- sparse masked phase (wave 0 only) ----------------
  if (!sOver) {
    if (tid < 64) {
      int lane = tid;
      int base = 0;
      for (int w = 0; w < MASKW; ++w) {
        ull avail = ~sRemv[w];
        int cnC = sCCnt[w];
        if (cnC > 0) {                       // lane-parallel cross pairs
          ull csup = 0;
          for (int k = lane; k < cnC; k += 64) {
            unsigned p = sCross[w][k];
            int ii = (int)(p & 0xFFFFu);
            int jl = (int)(p >> 16) & 63;
            if ((sKeptBits[ii >> 6] >> (ii & 63)) & 1ull) csup |= 1ull << jl;
          }
          csup = wave_or64(csup);
          avail &= ~csup;
        }
        int cnI = sICnt[w];
        ull kept;
        if (cnI == 0) {
          kept = avail;
        } else {
          ull dgT = 0ull;                    // my in-word suppressors
          for (int k = 0; k < cnI; ++k) {
            unsigned p = sIn[w][k];          // uniform LDS read
            int il = (int)(p & 63u);
            int jl = (int)(p >> 8) & 63;
            if (lane == jl) dgT |= 1ull << il;
          }
          ull cf = __ballot(((dgT & avail) != 0ull) && ((avail >> lane) & 1ull));
          if (cf == 0ull) {
            kept = avail;
          } else {
            kept = avail;
            while (true) {                   // fixpoint == greedy
              bool sup = (dgT & kept) != 0ull;
              ull kn = avail & ~__ballot(sup);
              if (kn == kept) break;
              kept = kn;
            }
          }
        }
        if (lane == 0) sKeptBits[w] = kept;  // same-wave order: visible later
        if ((kept >> lane) & 1ull) {
          int rank = base + (int)__popcll(kept & ((1ull << lane) - 1ull));
          if (rank < NPOST) sKeptList[rank] = (u16)(w * 64 + lane);
        }
        base += (int)__popcll(kept);
        if (base >= NPOST) break;            // ranks >=2000 never emitted
      }
      if (lane == 0) { sKeptBase = base; if (base >= NPOST) sStop = 1; }
    }
  }
  __syncthreads();

  // ---------------- dense fallback (correctness only) ----------------
  int startW = sOver ? 0 : MASKW;
  if (!sStop) {
    for (int w = startW; w < NWORDS; ++w) {
      if (tid < 64) { sWB[tid] = bs[w * 64 + tid]; sWA[tid] = area[w * 64 + tid]; }
      if (tid == 0) sSupW = sRemv[w];
      __syncthreads();
      int nk = sKeptBase;
      int c = tid & 63;
      for (int k0 = tid >> 6; k0 < nk; k0 += 4) {  // wave per kept box
        int ki = sKeptList[k0];
        float4 kb = bs[ki];                        // uniform load
        bool s = iou_gt_thr(kb, area[ki], sWB[c], sWA[c]);
        ull bits = __ballot(s);
        if (c == 0 && bits) atomicOr(&sSupW, bits);
      }
      __syncthreads();
      if (tid < 64) {
        int lane = tid;
        float4 bm = sWB[lane];
        float am = sWA[lane];
        ull dg = 0;
        for (int cc = lane + 1; cc < 64; ++cc)
          if (iou_gt_thr(bm, am, sWB[cc], sWA[cc])) dg |= 1ull << cc;
        ull avail = ~sSupW;
        ull kept = resolve_word(dg, avail, lane);
        int base = sKeptBase;
        if ((kept >> lane) & 1ull) {
          int rank = base + (int)__popcll(kept & ((1ull << lane) - 1ull));
          if (rank < NPOST) sKeptList[rank] = (u16)(w * 64 + lane);
        }
        if (lane == 0) {
          int nb = base + (int)__popcll(kept);
          sKeptBase = nb;
          if (nb >= NPOST) sStop = 1;
        }
      }
      __syncthreads();
      if (sStop) break;
    }
  }

  __syncthreads();
  int total = sKeptBase;
  if (total > NPOST) total = NPOST;
  for (int r = tid; r < NPOST; r += 256) {
    float4 v = make_float4(0.0f, 0.0f, 0.0f, 0.0f);
    if (r < total) v = bs[sKeptList[r]];
    reinterpret_cast<float4*>(out)[r] = v;
  }
}

// ---------------------------------------------------------------------------
extern "C" void kernel_launch(void* const* d_in, const int* in_sizes, int n_in,
                              void* d_out, int out_size, void* d_ws, size_t ws_size,
                              hipStream_t stream) {
  const float* locs   = (const float*)d_in[0];   // (8192,4) cy,cx,h,w
  const float* scores = (const float*)d_in[1];   // (8192,)

  char* ws = (char*)d_ws;
  u16*      partial  = (u16*)(ws + 0);
  float4*   bs       = (float4*)(ws + 131072);
  float*    area     = (float*)(ws + 262144);
  ull*      invBits  = (ull*)(ws + 294912);
  int*      ctrl     = (int*)(ws + 295936);
  int*      inCnt    = (int*)(ws + 296192);
  unsigned* crossBuf = (unsigned*)(ws + 296448);
  unsigned* inBuf    = (unsigned*)(ws + 321024);

  rankpart_kernel<<<dim3(N / 256, SPLIT), 256, 0, stream>>>(
      locs, scores, partial, invBits, ctrl, inCnt);
  gather_kernel<<<N / 256, 256, 0, stream>>>(locs, partial, bs, area, invBits);
  pairs_kernel<<<dim3(MASKW / 4, MASKW), 256, 0, stream>>>(
      bs, area, invBits, ctrl, inCnt, crossBuf, inBuf);
  scan_kernel<<<1, 256, 0, stream>>>(
      invBits, ctrl, inCnt, crossBuf, inBuf, bs, area, (float*)d_out);
}